// Round 1
// baseline (421.627 us; speedup 1.0000x reference)
//
#include <hip/hip_runtime.h>
#include <hip/hip_bf16.h>
#include <math.h>

#define B_ 8
#define T_ 2048
#define C_ 1024
#define H_ 64
#define M_ (B_*T_)   // 16384 rows

// ---------------------------------------------------------------------------
// Kernel 1: QKV projection.  x[M,C] @ {Wq,Wk,Wv}[C,64] -> q,k,v [M,64] (fp32)
// Block: 256 threads, 64 rows x 192 cols, K-chunks of 32 staged in LDS.
// Thread micro-tile: 4 rows x 12 cols (3 float4 groups).
// ---------------------------------------------------------------------------
__global__ __launch_bounds__(256) void qkv_kernel(
    const float* __restrict__ x,
    const float* __restrict__ Wq,
    const float* __restrict__ Wk,
    const float* __restrict__ Wv,
    float* __restrict__ qo,
    float* __restrict__ ko,
    float* __restrict__ vo)
{
    __shared__ float xt[32][64];    // xt[k][row]  (x chunk, transposed)
    __shared__ float wl[32][192];   // wl[k][col]  col = w*64+h

    const int t    = threadIdx.x;
    const int row0 = blockIdx.x * 64;
    const int tr   = t >> 4;        // 0..15 -> rows tr*4 .. tr*4+3
    const int tc   = t & 15;        // 0..15 -> cols tc*12 .. tc*12+11

    float acc[4][12];
    #pragma unroll
    for (int r = 0; r < 4; r++)
        #pragma unroll
        for (int c = 0; c < 12; c++) acc[r][c] = 0.0f;

    for (int k0 = 0; k0 < C_; k0 += 32) {
        __syncthreads();
        // stage x chunk: 64 rows x 32 k  (512 float4, 2 per thread), transpose
        #pragma unroll
        for (int i = 0; i < 2; i++) {
            const int f   = t + i * 256;
            const int row = f >> 3;        // 0..63
            const int kq  = f & 7;         // 0..7 (float4 index within 32 k)
            const float4 v4 = *(const float4*)(x + (size_t)(row0 + row) * C_ + k0 + kq * 4);
            xt[kq*4+0][row] = v4.x;
            xt[kq*4+1][row] = v4.y;
            xt[kq*4+2][row] = v4.z;
            xt[kq*4+3][row] = v4.w;
        }
        // stage W chunk: 3 x (32 k x 64)  (512 float4 each, 2 per thread)
        #pragma unroll
        for (int i = 0; i < 2; i++) {
            const int f  = t + i * 256;
            const int kk = f >> 4;         // 0..31
            const int cq = f & 15;         // 0..15
            const size_t off = (size_t)(k0 + kk) * H_ + cq * 4;
            *(float4*)&wl[kk][0*64 + cq*4] = *(const float4*)(Wq + off);
            *(float4*)&wl[kk][1*64 + cq*4] = *(const float4*)(Wk + off);
            *(float4*)&wl[kk][2*64 + cq*4] = *(const float4*)(Wv + off);
        }
        __syncthreads();

        #pragma unroll 8
        for (int kk = 0; kk < 32; kk++) {
            const float4 xv = *(const float4*)&xt[kk][tr*4];
            const float4 w0 = *(const float4*)&wl[kk][tc*12 + 0];
            const float4 w1 = *(const float4*)&wl[kk][tc*12 + 4];
            const float4 w2 = *(const float4*)&wl[kk][tc*12 + 8];
            const float xr[4]  = {xv.x, xv.y, xv.z, xv.w};
            const float wr[12] = {w0.x, w0.y, w0.z, w0.w,
                                  w1.x, w1.y, w1.z, w1.w,
                                  w2.x, w2.y, w2.z, w2.w};
            #pragma unroll
            for (int r = 0; r < 4; r++)
                #pragma unroll
                for (int c = 0; c < 12; c++)
                    acc[r][c] = fmaf(xr[r], wr[c], acc[r][c]);
        }
    }

    // epilogue: 3 float4 stores per row
    #pragma unroll
    for (int r = 0; r < 4; r++) {
        const int rowg = row0 + tr * 4 + r;
        #pragma unroll
        for (int g = 0; g < 3; g++) {
            const int col = tc * 12 + g * 4;   // 0..188, 4-aligned, no 64-cross
            const int w   = col >> 6;
            const int h   = col & 63;
            float* op = (w == 0) ? qo : ((w == 1) ? ko : vo);
            const float4 o4 = make_float4(acc[r][g*4+0], acc[r][g*4+1],
                                          acc[r][g*4+2], acc[r][g*4+3]);
            *(float4*)(op + (size_t)rowg * H_ + h) = o4;
        }
    }
}

// ---------------------------------------------------------------------------
// Kernel 2: causal flash attention with ALiBi, fp32.
// One block per (batch, 64-row q-tile). 256 threads.
// Score thread map: rr = t>>4 (4 rows), cc = t&15 (4 key cols) -> s[4][4].
// Output map reuses (rr rows, cc -> 4 head dims) -> O[4][4].
// ---------------------------------------------------------------------------
__global__ __launch_bounds__(256) void attn_kernel(
    const float* __restrict__ q,
    const float* __restrict__ k,
    const float* __restrict__ v,
    float* __restrict__ out)
{
    __shared__ float qT[64][64];   // qT[h][r]
    __shared__ float kT[64][64];   // kT[h][c]
    __shared__ float vl[64][64];   // vl[j][h]
    __shared__ float pT[64][68];   // pT[j][r], padded for conflict-free b128 rw

    const int t  = threadIdx.x;
    const int b  = blockIdx.x >> 5;
    const int qb = blockIdx.x & 31;
    const int rr = t >> 4;   // 0..15
    const int cc = t & 15;   // 0..15

    const size_t baseq = ((size_t)b * T_ + (size_t)qb * 64) * H_;

    // stage Q tile (scatter-transpose)
    {
        const int row = t >> 2;            // 0..63
        const int hq0 = (t & 3) * 4;
        #pragma unroll
        for (int u = 0; u < 4; u++) {
            const int hq = hq0 + u;        // 0..15
            const float4 v4 = *(const float4*)(q + baseq + (size_t)row * H_ + hq * 4);
            qT[hq*4+0][row] = v4.x;
            qT[hq*4+1][row] = v4.y;
            qT[hq*4+2][row] = v4.z;
            qT[hq*4+3][row] = v4.w;
        }
    }

    float O[4][4];
    float mrow[4], lrow[4];
    #pragma unroll
    for (int i = 0; i < 4; i++) {
        mrow[i] = -INFINITY;
        lrow[i] = 0.0f;
        #pragma unroll
        for (int h = 0; h < 4; h++) O[i][h] = 0.0f;
    }

    const float scale = 0.125f;                    // 64^-0.5
    const float slope = 0.70710678118654752f;      // 2^(-8*(0+1)/16)
    const int ig0 = qb * 64 + rr * 4;              // global q row base

    for (int kt = 0; kt <= qb; kt++) {
        const float* kbase = k + ((size_t)b * T_ + (size_t)kt * 64) * H_;
        const float* vbase = v + ((size_t)b * T_ + (size_t)kt * 64) * H_;

        __syncthreads();   // previous PV done with vl / pT
        // stage K tile (scatter-transpose)
        {
            const int row = t >> 2;
            const int hq0 = (t & 3) * 4;
            #pragma unroll
            for (int u = 0; u < 4; u++) {
                const int hq = hq0 + u;
                const float4 v4 = *(const float4*)(kbase + (size_t)row * H_ + hq * 4);
                kT[hq*4+0][row] = v4.x;
                kT[hq*4+1][row] = v4.y;
                kT[hq*4+2][row] = v4.z;
                kT[hq*4+3][row] = v4.w;
            }
        }
        // stage V tile (straight copy)
        #pragma unroll
        for (int i = 0; i < 4; i++) {
            const int f   = t + i * 256;
            const int row = f >> 4;        // 0..63
            const int hq  = f & 15;        // 0..15
            *(float4*)&vl[row][hq*4] = *(const float4*)(vbase + (size_t)row * H_ + hq * 4);
        }
        __syncthreads();

        // ---- S = Q K^T over 64 h ----
        float s[4][4];
        #pragma unroll
        for (int i = 0; i < 4; i++)
            #pragma unroll
            for (int j = 0; j < 4; j++) s[i][j] = 0.0f;

        #pragma unroll 8
        for (int h = 0; h < 64; h++) {
            const float4 qv = *(const float4*)&qT[h][rr*4];
            const float4 kv = *(const float4*)&kT[h][cc*4];
            const float qr[4] = {qv.x, qv.y, qv.z, qv.w};
            const float kr[4] = {kv.x, kv.y, kv.z, kv.w};
            #pragma unroll
            for (int i = 0; i < 4; i++)
                #pragma unroll
                for (int j = 0; j < 4; j++)
                    s[i][j] = fmaf(qr[i], kr[j], s[i][j]);
        }

        // ---- bias + mask + online softmax ----
        const int jg0 = kt * 64 + cc * 4;
        #pragma unroll
        for (int i = 0; i < 4; i++) {
            const int ig = ig0 + i;
            float mt = -INFINITY;
            #pragma unroll
            for (int j = 0; j < 4; j++) {
                const int jg = jg0 + j;
                float sv = (s[i][j] + (float)(jg - ig) * slope) * scale;
                if (jg > ig) sv = -INFINITY;     // only bites on diagonal tile
                s[i][j] = sv;
                mt = fmaxf(mt, sv);
            }
            // reduce max across the 16 cc lanes
            #pragma unroll
            for (int off = 1; off < 16; off <<= 1)
                mt = fmaxf(mt, __shfl_xor(mt, off, 64));

            const float mnew  = fmaxf(mrow[i], mt);
            const float alpha = __expf(mrow[i] - mnew);
            mrow[i] = mnew;

            float rsum = 0.0f;
            #pragma unroll
            for (int j = 0; j < 4; j++) {
                const float p = __expf(s[i][j] - mnew);
                s[i][j] = p;
                rsum += p;
            }
            #pragma unroll
            for (int off = 1; off < 16; off <<= 1)
                rsum += __shfl_xor(rsum, off, 64);

            lrow[i] = lrow[i] * alpha + rsum;
            #pragma unroll
            for (int h = 0; h < 4; h++) O[i][h] *= alpha;
        }

        // ---- write P (transposed) ----
        #pragma unroll
        for (int jj = 0; jj < 4; jj++) {
            const float4 p4 = make_float4(s[0][jj], s[1][jj], s[2][jj], s[3][jj]);
            *(float4*)&pT[cc*4 + jj][rr*4] = p4;
        }
        __syncthreads();

        // ---- O += P V ----
        #pragma unroll 8
        for (int j = 0; j < 64; j++) {
            const float4 pv = *(const float4*)&pT[j][rr*4];
            const float4 vv = *(const float4*)&vl[j][cc*4];
            const float pr[4] = {pv.x, pv.y, pv.z, pv.w};
            const float vr[4] = {vv.x, vv.y, vv.z, vv.w};
            #pragma unroll
            for (int i = 0; i < 4; i++)
                #pragma unroll
                for (int h = 0; h < 4; h++)
                    O[i][h] = fmaf(pr[i], vr[h], O[i][h]);
        }
    }

    // ---- finalize: divide by l, store ----
    #pragma unroll
    for (int i = 0; i < 4; i++) {
        const float inv = 1.0f / lrow[i];
        const float4 o4 = make_float4(O[i][0] * inv, O[i][1] * inv,
                                      O[i][2] * inv, O[i][3] * inv);
        *(float4*)(out + baseq + (size_t)(rr*4 + i) * H_ + cc * 4) = o4;
    }
}

extern "C" void kernel_launch(void* const* d_in, const int* in_sizes, int n_in,
                              void* d_out, int out_size, void* d_ws, size_t ws_size,
                              hipStream_t stream) {
    (void)in_sizes; (void)n_in; (void)out_size; (void)ws_size;
    const float* x  = (const float*)d_in[0];
    const float* Wq = (const float*)d_in[1];
    const float* Wk = (const float*)d_in[2];
    const float* Wv = (const float*)d_in[3];
    float* out = (float*)d_out;

    float* q_ws = (float*)d_ws;                      // [M,64]
    float* k_ws = q_ws + (size_t)M_ * H_;            // [M,64]
    float* v_ws = k_ws + (size_t)M_ * H_;            // [M,64]

    qkv_kernel<<<M_ / 64, 256, 0, stream>>>(x, Wq, Wk, Wv, q_ws, k_ws, v_ws);
    attn_kernel<<<B_ * 32, 256, 0, stream>>>(q_ws, k_ws, v_ws, out);
}

// Round 2
// 192.418 us; speedup vs baseline: 2.1912x; 2.1912x over previous
//
#include <hip/hip_runtime.h>
#include <hip/hip_bf16.h>
#include <math.h>

#define B_ 8
#define T_ 2048
#define C_ 1024
#define H_ 64
#define M_ (B_*T_)   // 16384 rows

typedef __attribute__((ext_vector_type(8))) short bf16x8;
typedef __attribute__((ext_vector_type(4))) float floatx4;

// fp32 -> bf16 round-to-nearest-even (3 VALU ops)
static __device__ __forceinline__ unsigned short f2bf(float f) {
    union { float f; unsigned u; } v; v.f = f;
    unsigned r = v.u + 0x7fffu + ((v.u >> 16) & 1u);
    return (unsigned short)(r >> 16);
}
static __device__ __forceinline__ unsigned pk2(float lo, float hi) {
    return (unsigned)f2bf(lo) | ((unsigned)f2bf(hi) << 16);
}

// ---------------------------------------------------------------------------
// Kernel 0: W prep. W{q,k,v}[1024,64] fp32 -> wt[192][1024] bf16 (transposed).
// wt row c: c<64 -> Wq col c; 64..127 -> Wk; 128..191 -> Wv.
// ---------------------------------------------------------------------------
__global__ __launch_bounds__(256) void wprep_kernel(
    const float* __restrict__ Wq, const float* __restrict__ Wk,
    const float* __restrict__ Wv, unsigned short* __restrict__ wt)
{
    const int c = blockIdx.x;                 // 0..191
    const float* W = (c < 64) ? Wq : ((c < 128) ? Wk : Wv);
    const int col = c & 63;
    const int t = threadIdx.x;
    #pragma unroll
    for (int i = 0; i < 4; i++) {
        const int k = t + i * 256;
        wt[c * 1024 + k] = f2bf(W[(size_t)k * 64 + col]);
    }
}

// ---------------------------------------------------------------------------
// Kernel 1: QKV projection, bf16 MFMA.  64 rows/block, 256 thr (4 waves),
// wave w owns row-stripe w*16, all 12 col-tiles (192 cols = q|k|v).
// Outputs: q,k bf16 [row][64] (q pre-scaled by 0.125), v bf16 TRANSPOSED
// [b][h][t] so the attention kernel's PV B-operand loads are contiguous.
// ---------------------------------------------------------------------------
__global__ __launch_bounds__(256) void qkv_kernel(
    const float* __restrict__ x, const unsigned short* __restrict__ wt,
    unsigned short* __restrict__ qo, unsigned short* __restrict__ ko,
    unsigned short* __restrict__ vo)
{
    __shared__ __align__(16) unsigned short smem[64*64 + 192*64]; // 32 KB
    // views: xs[row 64][k 64] at 0; ws[col 192][k 64] at 4096;
    // epilogue view es[row 64][col 200] (12800 <= 16384)
    #define XS_(r,k_) smem[(r)*64 + (k_)]
    #define WS_(c,k_) smem[4096 + (c)*64 + (k_)]
    #define ES_(r,c)  smem[(r)*200 + (c)]

    const int t    = threadIdx.x;
    const int r0   = blockIdx.x * 64;
    const int w    = t >> 6;
    const int lane = t & 63;
    const int l15  = lane & 15;
    const int quad = lane >> 4;

    floatx4 acc[12];
    #pragma unroll
    for (int i = 0; i < 12; i++) acc[i] = (floatx4)(0.0f);

    for (int k0 = 0; k0 < C_; k0 += 64) {
        __syncthreads();
        // stage x: 64 rows x 64 k, fp32->bf16, 16 floats/thread
        {
            const int row = t >> 2;
            const int kq  = (t & 3) * 16;
            const float* xp = x + (size_t)(r0 + row) * C_ + k0 + kq;
            const float4 a = *(const float4*)(xp + 0);
            const float4 b = *(const float4*)(xp + 4);
            const float4 c = *(const float4*)(xp + 8);
            const float4 d = *(const float4*)(xp + 12);
            uint4 lo = { pk2(a.x,a.y), pk2(a.z,a.w), pk2(b.x,b.y), pk2(b.z,b.w) };
            uint4 hi = { pk2(c.x,c.y), pk2(c.z,c.w), pk2(d.x,d.y), pk2(d.z,d.w) };
            *(uint4*)&XS_(row, kq)     = lo;
            *(uint4*)&XS_(row, kq + 8) = hi;
        }
        // stage wt: 192 cols x 64 k bf16 copy, 6 x b128 per thread
        #pragma unroll
        for (int i = 0; i < 6; i++) {
            const int fo  = t + i * 256;      // 0..1535
            const int col = fo >> 3;
            const int oct = fo & 7;
            *(uint4*)&WS_(col, oct * 8) =
                *(const uint4*)&wt[col * 1024 + k0 + oct * 8];
        }
        __syncthreads();

        #pragma unroll
        for (int ks = 0; ks < 2; ks++) {
            const bf16x8 af = *(const bf16x8*)&XS_(w*16 + l15, ks*32 + quad*8);
            #pragma unroll
            for (int nt = 0; nt < 12; nt++) {
                const bf16x8 bf = *(const bf16x8*)&WS_(nt*16 + l15, ks*32 + quad*8);
                acc[nt] = __builtin_amdgcn_mfma_f32_16x16x32_bf16(af, bf, acc[nt], 0, 0, 0);
            }
        }
    }

    // ---- epilogue: dump all 192 cols to LDS (bf16), then coalesced writes ----
    __syncthreads();
    #pragma unroll
    for (int nt = 0; nt < 12; nt++) {
        const float sc = (nt < 4) ? 0.125f : 1.0f;   // fold 1/sqrt(64) into q
        #pragma unroll
        for (int r = 0; r < 4; r++)
            ES_(w*16 + quad*4 + r, nt*16 + l15) = f2bf(acc[nt][r] * sc);
    }
    __syncthreads();

    // q, k: straight [row][64] bf16
    #pragma unroll
    for (int m = 0; m < 2; m++) {
        unsigned short* outp = m ? ko : qo;
        #pragma unroll
        for (int i = 0; i < 2; i++) {
            const int fo  = t + i * 256;      // 0..511
            const int row = fo >> 3;
            const int oct = fo & 7;
            *(uint4*)&outp[(size_t)(r0 + row) * 64 + oct * 8] =
                *(const uint4*)&ES_(row, m * 64 + oct * 8);
        }
    }
    // v: transposed [b][h][t]
    {
        const int h  = t >> 2;               // 0..63
        const int ts = (t & 3) * 16;         // t-offset within the 64-row tile
        const int b  = r0 >> 11;
        const int tt = r0 & 2047;
        unsigned short vtmp[16];
        #pragma unroll
        for (int j = 0; j < 16; j++) vtmp[j] = ES_(ts + j, 128 + h);
        #pragma unroll
        for (int j = 0; j < 2; j++)
            *(uint4*)&vo[((size_t)b * 64 + h) * 2048 + tt + ts + j * 8] =
                *(uint4*)&vtmp[j * 8];
    }
    #undef XS_
    #undef WS_
    #undef ES_
}

// ---------------------------------------------------------------------------
// Kernel 2: causal flash attention with ALiBi, bf16 MFMA.
// 32-row q-tile per block, 128 threads (2 waves, 16 q-rows each).
// Grid 512 = 8 batches x 64 q-tiles, launched heavy-first for balance.
// ---------------------------------------------------------------------------
__global__ __launch_bounds__(128) void attn_kernel(
    const unsigned short* __restrict__ q,
    const unsigned short* __restrict__ k,
    const unsigned short* __restrict__ vT,
    float* __restrict__ out)
{
    __shared__ __align__(16) unsigned short qs[32*64];   // [qrow][h]
    __shared__ __align__(16) unsigned short ks[64*64];   // [key][h]
    __shared__ __align__(16) unsigned short vs[64*64];   // [h][key]  (V^T)
    __shared__ __align__(16) unsigned short pT[32*72];   // [qrow][key], pad->4-way max

    const int t    = threadIdx.x;
    const int w    = t >> 6;      // 0,1
    const int lane = t & 63;
    const int l15  = lane & 15;
    const int quad = lane >> 4;

    const int b  = blockIdx.x & 7;
    const int qt = 63 - (blockIdx.x >> 3);   // heavy tiles first
    const int q0 = qt * 32;
    const size_t qbase = ((size_t)b * T_ + q0) * 64;

    // stage Q (32x64), load per-wave A-fragments once (held whole kernel)
    {
        const int row = t >> 2;
        const int kq  = (t & 3) * 16;
        *(uint4*)&qs[row*64 + kq]     = *(const uint4*)&q[qbase + row*64 + kq];
        *(uint4*)&qs[row*64 + kq + 8] = *(const uint4*)&q[qbase + row*64 + kq + 8];
    }
    __syncthreads();
    bf16x8 qf[2];
    qf[0] = *(const bf16x8*)&qs[(w*16 + l15)*64 + 0  + quad*8];
    qf[1] = *(const bf16x8*)&qs[(w*16 + l15)*64 + 32 + quad*8];

    floatx4 O[4];
    #pragma unroll
    for (int i = 0; i < 4; i++) O[i] = (floatx4)(0.0f);
    float mrow[4], lrow[4];
    #pragma unroll
    for (int r = 0; r < 4; r++) { mrow[r] = -INFINITY; lrow[r] = 0.0f; }

    const int   nkt = (q0 + 31) / 64 + 1;
    const float bs  = 0.088388347648318447f;      // 2^-0.5 * 0.125 (alibi*scale)
    const int   igl = q0 + w*16 + quad*4;         // +r = global q row (in-batch)

    for (int kt = 0; kt < nkt; kt++) {
        __syncthreads();
        // stage K tile [64 keys][64 h] and V^T tile [64 h][64 keys]
        {
            const int row = t >> 1;
            const int ob  = (t & 1) * 4;
            const unsigned short* kp = k  + ((size_t)b * T_ + kt*64 + row) * 64;
            const unsigned short* vp = vT + ((size_t)b * 64 + row) * 2048 + kt*64;
            #pragma unroll
            for (int i = 0; i < 4; i++) {
                *(uint4*)&ks[row*64 + (ob+i)*8] = *(const uint4*)&kp[(ob+i)*8];
                *(uint4*)&vs[row*64 + (ob+i)*8] = *(const uint4*)&vp[(ob+i)*8];
            }
        }
        __syncthreads();

        // ---- S = Q K^T (scale pre-folded into q) ----
        floatx4 s[4];
        #pragma unroll
        for (int nt = 0; nt < 4; nt++) {
            const bf16x8 kf0 = *(const bf16x8*)&ks[(nt*16 + l15)*64 + 0  + quad*8];
            const bf16x8 kf1 = *(const bf16x8*)&ks[(nt*16 + l15)*64 + 32 + quad*8];
            floatx4 z = (floatx4)(0.0f);
            z = __builtin_amdgcn_mfma_f32_16x16x32_bf16(qf[0], kf0, z, 0, 0, 0);
            z = __builtin_amdgcn_mfma_f32_16x16x32_bf16(qf[1], kf1, z, 0, 0, 0);
            s[nt] = z;
        }

        // ---- ALiBi bias + causal mask + online softmax (rows quad*4+r) ----
        #pragma unroll
        for (int r = 0; r < 4; r++) {
            const int   ig    = igl + r;
            const float dbase = (float)(kt*64 + l15 - ig);
            float sv[4];
            float mloc = -INFINITY;
            #pragma unroll
            for (int nt = 0; nt < 4; nt++) {
                float xv = s[nt][r] + (dbase + (float)(nt*16)) * bs;
                if (kt*64 + nt*16 + l15 > ig) xv = -INFINITY;
                sv[nt] = xv;
                mloc = fmaxf(mloc, xv);
            }
            #pragma unroll
            for (int off = 1; off < 16; off <<= 1)
                mloc = fmaxf(mloc, __shfl_xor(mloc, off));
            const float mnew  = fmaxf(mrow[r], mloc);
            const float alpha = __expf(mrow[r] - mnew);
            mrow[r] = mnew;
            float rs = 0.0f;
            #pragma unroll
            for (int nt = 0; nt < 4; nt++) {
                const float p = __expf(sv[nt] - mnew);
                rs += p;
                pT[(w*16 + quad*4 + r)*72 + nt*16 + l15] = f2bf(p);
            }
            #pragma unroll
            for (int off = 1; off < 16; off <<= 1)
                rs += __shfl_xor(rs, off);
            lrow[r] = lrow[r] * alpha + rs;
            #pragma unroll
            for (int nt = 0; nt < 4; nt++) O[nt][r] *= alpha;
        }

        // ---- O += P V  (A = pT stripe, same-wave LDS round-trip; B = V^T) ----
        #pragma unroll
        for (int ks2 = 0; ks2 < 2; ks2++) {
            const bf16x8 pf = *(const bf16x8*)&pT[(w*16 + l15)*72 + ks2*32 + quad*8];
            #pragma unroll
            for (int nt = 0; nt < 4; nt++) {
                const bf16x8 vf = *(const bf16x8*)&vs[(nt*16 + l15)*64 + ks2*32 + quad*8];
                O[nt] = __builtin_amdgcn_mfma_f32_16x16x32_bf16(pf, vf, O[nt], 0, 0, 0);
            }
        }
    }

    // ---- finalize ----
    #pragma unroll
    for (int r = 0; r < 4; r++) {
        const float inv = 1.0f / lrow[r];
        const int qrow = q0 + w*16 + quad*4 + r;
        #pragma unroll
        for (int nt = 0; nt < 4; nt++)
            out[((size_t)b * T_ + qrow) * 64 + nt*16 + l15] = O[nt][r] * inv;
    }
}

extern "C" void kernel_launch(void* const* d_in, const int* in_sizes, int n_in,
                              void* d_out, int out_size, void* d_ws, size_t ws_size,
                              hipStream_t stream) {
    (void)in_sizes; (void)n_in; (void)out_size; (void)ws_size;
    const float* x  = (const float*)d_in[0];
    const float* Wq = (const float*)d_in[1];
    const float* Wk = (const float*)d_in[2];
    const float* Wv = (const float*)d_in[3];
    float* out = (float*)d_out;

    unsigned short* wt = (unsigned short*)d_ws;                 // [192][1024]
    unsigned short* qw = wt + 196608;                           // [M][64]
    unsigned short* kw = qw + (size_t)M_ * H_;                  // [M][64]
    unsigned short* vw = kw + (size_t)M_ * H_;                  // [B][64][2048]

    wprep_kernel<<<192, 256, 0, stream>>>(Wq, Wk, Wv, wt);
    qkv_kernel<<<M_ / 64, 256, 0, stream>>>(x, wt, qw, kw, vw);
    attn_kernel<<<B_ * 64, 128, 0, stream>>>(qw, kw, vw, out);
}